// Round 3
// baseline (172.352 us; speedup 1.0000x reference)
//
#include <hip/hip_runtime.h>
#include <hip/hip_bf16.h>
#include <stdint.h>

// Problem constants
#define D_MODEL 1024
#define BATCH   4
#define SEQ     4096
#define M_TOTAL (BATCH*SEQ)   // 16384
#define KDIM    1024
#define NTOT    2048          // combined N (z cols 0..1023, h cols 1024..2047)

// Scan chunking
#define NC 128
#define CL (SEQ/NC)           // 32

// GEMM tiling: 256x256 tile, BK=64, 8 waves (2M x 4N), 8-phase pipeline
#define BM 256
#define BN 256
#define BK2 64
#define NKT (KDIM/BK2)        // 16 K-tiles

typedef __bf16 bf16x8 __attribute__((ext_vector_type(8)));
typedef float  f32x4  __attribute__((ext_vector_type(4)));
typedef unsigned short u16x4 __attribute__((ext_vector_type(4)));

static __device__ __forceinline__ unsigned short f2bf(float f) {
  unsigned u = __builtin_bit_cast(unsigned, f);
  u += 0x7FFFu + ((u >> 16) & 1u);     // round-to-nearest-even
  return (unsigned short)(u >> 16);
}
static __device__ __forceinline__ float bf2f(unsigned short u) {
  return __builtin_bit_cast(float, (unsigned)u << 16);
}

// ---------------- K0a: x (fp32) -> bf16 ----------------
__global__ __launch_bounds__(256) void k_cvt_x(const float* __restrict__ x,
                                               unsigned short* __restrict__ xb) {
  int i = blockIdx.x * 256 + threadIdx.x;          // 4 elems each
  float4 v = ((const float4*)x)[i];
  ushort4 o;
  o.x = f2bf(v.x); o.y = f2bf(v.y); o.z = f2bf(v.z); o.w = f2bf(v.w);
  ((ushort4*)xb)[i] = o;
}

// ---------------- K0b: W (fp32 [d][e]) -> bf16 transposed [e][d] ----------------
__global__ void k_cvt_wT(const float* __restrict__ Wz, const float* __restrict__ Wh,
                         unsigned short* __restrict__ WzT, unsigned short* __restrict__ WhT) {
  __shared__ float tile[32][33];
  const float* W = blockIdx.z ? Wh : Wz;
  unsigned short* O = blockIdx.z ? WhT : WzT;
  int bx = blockIdx.x * 32;   // e base
  int by = blockIdx.y * 32;   // d base
  int tx = threadIdx.x, ty = threadIdx.y; // 32 x 8
  for (int yy = ty; yy < 32; yy += 8)
    tile[yy][tx] = W[(size_t)(by + yy) * D_MODEL + bx + tx];
  __syncthreads();
  for (int yy = ty; yy < 32; yy += 8)
    O[(size_t)(bx + yy) * D_MODEL + by + tx] = f2bf(tile[tx][yy]);
}

// ---------------- K1: GEMM  [P|Q](bf16) = xb @ Wall^T, 8-phase pipeline ---------
// LDS (128 KB): 2 K-tile buffers x [A 32KB | B 32KB], each split in K-halves
// (ks=0: k 0..31, ks=1: k 32..63). Fragment-major within a K-half:
//   shorts index = region + ks*8192 + c*2048 + row*8   (c = k-chunk 0..3)
// -> ds_read_b128 conflict-free (16 lanes read 256B contiguous) AND
//    global_load_lds dest is linear (wave-uniform base + lane*16B).
// Phases per K-tile t (16 MFMA each, raw barriers, setprio, counted vmcnt):
//  P1: rd A[0-3]ks0 + B[0-3]ks0 | stage A.ks1(t+1) | MFMA acc[0-3]
//  P2: rd A[4-7]ks0             | stage B.ks1(t+1) | MFMA acc[4-7] | vmcnt(8)
//  P3: rd A[0-3]ks1 + B[0-3]ks1 | stage A.ks0(t+2) | MFMA acc[0-3]
//  P4: rd A[4-7]ks1             | stage B.ks0(t+2) | MFMA acc[4-7] | vmcnt(8)
// Safety: tile t's ksX region reads complete at that phase-pair's lgkmcnt
// before its closing barrier; t+2's stage into that region issues only after.
__global__ __launch_bounds__(512, 2) void k_gemm8(
    const unsigned short* __restrict__ xb,    // [M][K] bf16
    const unsigned short* __restrict__ Wall,  // [2048][K] bf16 ([WzT;WhT])
    unsigned short* __restrict__ P, unsigned short* __restrict__ Q)
{
  __shared__ __attribute__((aligned(16))) unsigned short lds[65536]; // 128 KB

  const int tid  = threadIdx.x;
  const int wave = tid >> 6;
  const int lane = tid & 63;
  const int m0 = blockIdx.x * BM;
  const int n0 = blockIdx.y * BN;
  const int wr = wave >> 2;            // 0..1  (128 rows)
  const int wc = wave & 3;             // 0..3  (64 cols)
  const int lr = lane & 15;
  const int lc = lane >> 4;            // k-chunk 0..3

  f32x4 acc[8][4];
  #pragma unroll
  for (int i = 0; i < 8; ++i)
    #pragma unroll
    for (int j = 0; j < 4; ++j) acc[i][j] = (f32x4){0.f, 0.f, 0.f, 0.f};

  // stage one K-half unit (16KB): 2 x global_load_lds(16B) per thread
  auto stage = [&](const unsigned short* __restrict__ src, int rowbase,
                   int kt, int ks, int regionShorts) {
    #pragma unroll
    for (int l = 0; l < 2; ++l) {
      const int s   = l * 512 + wave * 64 + lane;   // slot 0..1023
      const int row = s & 255;
      const int c   = s >> 8;                        // wave-uniform
      const unsigned short* g = src + (size_t)(rowbase + row) * KDIM + kt * BK2 + ks * 32 + c * 8;
      __builtin_amdgcn_global_load_lds(
          (const __attribute__((address_space(1))) unsigned int*)g,
          (__attribute__((address_space(3))) unsigned int*)(lds + regionShorts + ks * 8192 + (l * 512 + wave * 64) * 8),
          16, 0, 0);
    }
  };

  const int aFragBase = lc * 2048 + (wr * 128 + lr) * 8;  // + ks*8192 + mf*128 (+region)
  const int bFragBase = lc * 2048 + (wc * 64  + lr) * 8;  // + ks*8192 + nf*128 (+region+16384)

  // ---- prologue: tile0 (4 units) + tile1 ks0 (2 units); wait tile0 ----
  stage(xb,   m0, 0, 0, 0);         // A.ks0(0)
  stage(Wall, n0, 0, 0, 16384);     // B.ks0(0)
  stage(xb,   m0, 0, 1, 0);         // A.ks1(0)
  stage(Wall, n0, 0, 1, 16384);     // B.ks1(0)
  stage(xb,   m0, 1, 0, 32768);     // A.ks0(1)
  stage(Wall, n0, 1, 0, 49152);     // B.ks0(1)
  asm volatile("s_waitcnt vmcnt(4)" ::: "memory");
  __builtin_amdgcn_s_barrier();

  for (int kt = 0; kt < NKT; ++kt) {
    const int buf  = (kt & 1) << 15;       // 0 / 32768
    const int nbuf = 32768 - buf;
    bf16x8 a0[4], a1[4], b0[4];

    // ---- P1 ----
    #pragma unroll
    for (int nf = 0; nf < 4; ++nf)
      b0[nf] = *(const bf16x8*)(lds + buf + 16384 + bFragBase + nf * 128);
    #pragma unroll
    for (int mf = 0; mf < 4; ++mf)
      a0[mf] = *(const bf16x8*)(lds + buf + aFragBase + mf * 128);
    if (kt + 1 < NKT) stage(xb, m0, kt + 1, 1, nbuf);
    __builtin_amdgcn_s_barrier();
    __builtin_amdgcn_s_setprio(1);
    #pragma unroll
    for (int mf = 0; mf < 4; ++mf)
      #pragma unroll
      for (int nf = 0; nf < 4; ++nf)
        acc[mf][nf] = __builtin_amdgcn_mfma_f32_16x16x32_bf16(a0[mf], b0[nf], acc[mf][nf], 0, 0, 0);
    __builtin_amdgcn_s_setprio(0);
    __builtin_amdgcn_s_barrier();

    // ---- P2 ----
    #pragma unroll
    for (int mf = 0; mf < 4; ++mf)
      a1[mf] = *(const bf16x8*)(lds + buf + aFragBase + (mf + 4) * 128);
    if (kt + 1 < NKT) stage(Wall, n0, kt + 1, 1, nbuf + 16384);
    __builtin_amdgcn_s_barrier();
    __builtin_amdgcn_s_setprio(1);
    #pragma unroll
    for (int mf = 0; mf < 4; ++mf)
      #pragma unroll
      for (int nf = 0; nf < 4; ++nf)
        acc[mf + 4][nf] = __builtin_amdgcn_mfma_f32_16x16x32_bf16(a1[mf], b0[nf], acc[mf + 4][nf], 0, 0, 0);
    __builtin_amdgcn_s_setprio(0);
    if (kt + 1 < NKT) asm volatile("s_waitcnt vmcnt(8)" ::: "memory");
    else              asm volatile("s_waitcnt vmcnt(0)" ::: "memory");
    __builtin_amdgcn_s_barrier();

    // ---- P3 ----
    #pragma unroll
    for (int nf = 0; nf < 4; ++nf)
      b0[nf] = *(const bf16x8*)(lds + buf + 16384 + 8192 + bFragBase + nf * 128);
    #pragma unroll
    for (int mf = 0; mf < 4; ++mf)
      a0[mf] = *(const bf16x8*)(lds + buf + 8192 + aFragBase + mf * 128);
    if (kt + 2 < NKT) stage(xb, m0, kt + 2, 0, buf);
    __builtin_amdgcn_s_barrier();
    __builtin_amdgcn_s_setprio(1);
    #pragma unroll
    for (int mf = 0; mf < 4; ++mf)
      #pragma unroll
      for (int nf = 0; nf < 4; ++nf)
        acc[mf][nf] = __builtin_amdgcn_mfma_f32_16x16x32_bf16(a0[mf], b0[nf], acc[mf][nf], 0, 0, 0);
    __builtin_amdgcn_s_setprio(0);
    __builtin_amdgcn_s_barrier();

    // ---- P4 ----
    #pragma unroll
    for (int mf = 0; mf < 4; ++mf)
      a1[mf] = *(const bf16x8*)(lds + buf + 8192 + aFragBase + (mf + 4) * 128);
    if (kt + 2 < NKT) stage(Wall, n0, kt + 2, 0, buf + 16384);
    __builtin_amdgcn_s_barrier();
    __builtin_amdgcn_s_setprio(1);
    #pragma unroll
    for (int mf = 0; mf < 4; ++mf)
      #pragma unroll
      for (int nf = 0; nf < 4; ++nf)
        acc[mf + 4][nf] = __builtin_amdgcn_mfma_f32_16x16x32_bf16(a1[mf], b0[nf], acc[mf + 4][nf], 0, 0, 0);
    __builtin_amdgcn_s_setprio(0);
    if (kt + 2 < NKT)      asm volatile("s_waitcnt vmcnt(8)" ::: "memory");
    else if (kt + 1 < NKT) asm volatile("s_waitcnt vmcnt(4)" ::: "memory");
    __builtin_amdgcn_s_barrier();
  }

  // epilogue: C/D layout col = lane&15, row = 4*(lane>>4)+r
  unsigned short* Cout = (n0 < 1024) ? P : Q;
  const int colb = (n0 < 1024) ? n0 : (n0 - 1024);
  const int cb = lane & 15;
  const int rb4 = (lane >> 4) * 4;
  #pragma unroll
  for (int mf = 0; mf < 8; ++mf) {
    #pragma unroll
    for (int nf = 0; nf < 4; ++nf) {
      const size_t col  = (size_t)(colb + wc * 64 + nf * 16 + cb);
      const size_t row0 = (size_t)(m0 + wr * 128 + mf * 16 + rb4);
      #pragma unroll
      for (int r = 0; r < 4; ++r)
        Cout[(row0 + r) * D_MODEL + col] = f2bf(acc[mf][nf][r]);
    }
  }
}

// ---------------- K2: per-chunk scan aggregates (bf16 preacts) -----------------
__global__ __launch_bounds__(256) void k_scan_agg(
    const unsigned short* __restrict__ P, const unsigned short* __restrict__ Q,
    const float* __restrict__ bz, const float* __restrict__ bh,
    float* __restrict__ Aagg, float* __restrict__ Bagg)
{
  int c = blockIdx.x & (NC - 1);
  int b = blockIdx.x >> 7;
  int d = threadIdx.x * 4;
  f32x4 vbz = *(const f32x4*)(bz + d);
  f32x4 vbh = *(const f32x4*)(bh + d);
  f32x4 A = {1.f, 1.f, 1.f, 1.f}, Bv = {0.f, 0.f, 0.f, 0.f};
  size_t base = ((size_t)b * SEQ + (size_t)c * CL) * D_MODEL + d;
  for (int t = 0; t < CL; ++t) {
    u16x4 pu = *(const u16x4*)(P + base + (size_t)t * D_MODEL);
    u16x4 qu = *(const u16x4*)(Q + base + (size_t)t * D_MODEL);
    #pragma unroll
    for (int r = 0; r < 4; ++r) {
      float z = 1.f / (1.f + __expf(-(bf2f(pu[r]) + vbz[r])));
      float a = 1.f - z;
      float bb = z * (bf2f(qu[r]) + vbh[r]);
      Bv[r] = a * Bv[r] + bb;
      A[r]  = a * A[r];
    }
  }
  size_t o = ((size_t)b * NC + c) * D_MODEL + d;
  *(f32x4*)(Aagg + o) = A;
  *(f32x4*)(Bagg + o) = Bv;
}

// ---------------- K3: scan across chunk aggregates ----------------
__global__ __launch_bounds__(256) void k_scan_chunks(
    const float* __restrict__ Aagg, const float* __restrict__ Bagg,
    float* __restrict__ Pref)
{
  int idx = blockIdx.x * 256 + threadIdx.x;  // b*1024 + d
  int b = idx >> 10, d = idx & 1023;
  float h = 0.f;
  for (int cc = 0; cc < NC; ++cc) {
    size_t o = ((size_t)b * NC + cc) * D_MODEL + d;
    Pref[o] = h;
    h = Aagg[o] * h + Bagg[o];
  }
}

// ---------------- K4: apply scan, write fp32 h to d_out ----------------
__global__ __launch_bounds__(256) void k_scan_apply(
    const unsigned short* __restrict__ P, const unsigned short* __restrict__ Q,
    const float* __restrict__ bz, const float* __restrict__ bh,
    const float* __restrict__ Pref, float* __restrict__ out)
{
  int c = blockIdx.x & (NC - 1);
  int b = blockIdx.x >> 7;
  int d = threadIdx.x * 4;
  f32x4 vbz = *(const f32x4*)(bz + d);
  f32x4 vbh = *(const f32x4*)(bh + d);
  f32x4 h = *(const f32x4*)(Pref + ((size_t)b * NC + c) * D_MODEL + d);
  size_t base = ((size_t)b * SEQ + (size_t)c * CL) * D_MODEL + d;
  for (int t = 0; t < CL; ++t) {
    u16x4 pu = *(const u16x4*)(P + base + (size_t)t * D_MODEL);
    u16x4 qu = *(const u16x4*)(Q + base + (size_t)t * D_MODEL);
    #pragma unroll
    for (int r = 0; r < 4; ++r) {
      float z = 1.f / (1.f + __expf(-(bf2f(pu[r]) + vbz[r])));
      float a = 1.f - z;
      h[r] = a * h[r] + z * (bf2f(qu[r]) + vbh[r]);
    }
    *(f32x4*)(out + base + (size_t)t * D_MODEL) = h;
  }
}

extern "C" void kernel_launch(void* const* d_in, const int* in_sizes, int n_in,
                              void* d_out, int out_size, void* d_ws, size_t ws_size,
                              hipStream_t stream)
{
  const float* x  = (const float*)d_in[0];
  const float* Wz = (const float*)d_in[1];
  const float* bz = (const float*)d_in[2];
  const float* Wh = (const float*)d_in[3];
  const float* bh = (const float*)d_in[4];

  char* ws = (char*)d_ws;
  unsigned short* xb   = (unsigned short*)(ws);               // 33,554,432
  unsigned short* Wall = (unsigned short*)(ws + 33554432);    //  4,194,304 ([WzT;WhT])
  unsigned short* Pb   = (unsigned short*)(ws + 37748736);    // 33,554,432 (z-preact bf16)
  unsigned short* Qb   = (unsigned short*)(ws + 71303168);    // 33,554,432 (h-preact bf16)
  float* Aagg = (float*)(ws + 104857600);                     //  2,097,152
  float* Bagg = (float*)(ws + 106954752);                     //  2,097,152
  float* Pref = (float*)(ws + 109051904);                     //  2,097,152
  float* out  = (float*)d_out;

  k_cvt_x<<<M_TOTAL * D_MODEL / 4 / 256, 256, 0, stream>>>(x, xb);
  k_cvt_wT<<<dim3(32, 32, 2), dim3(32, 8), 0, stream>>>(Wz, Wh, Wall, Wall + (size_t)1024 * 1024);
  k_gemm8<<<dim3(M_TOTAL / BM, NTOT / BN), 512, 0, stream>>>(xb, Wall, Pb, Qb);
  k_scan_agg<<<BATCH * NC, 256, 0, stream>>>(Pb, Qb, bz, bh, Aagg, Bagg);
  k_scan_chunks<<<BATCH * D_MODEL / 256, 256, 0, stream>>>(Aagg, Bagg, Pref);
  k_scan_apply<<<BATCH * NC, 256, 0, stream>>>(Pb, Qb, bz, bh, Pref, out);
}